// Round 4
// baseline (181.325 us; speedup 1.0000x reference)
//
#include <hip/hip_runtime.h>
#include <hip/hip_bf16.h>
#include <stdint.h>
#include <stddef.h>

typedef __bf16 bf16;
typedef __attribute__((ext_vector_type(4))) __bf16 bf16x4;
typedef __attribute__((ext_vector_type(8))) __bf16 bf16x8;
typedef __attribute__((ext_vector_type(4))) float f32x4;
typedef __attribute__((ext_vector_type(16))) float f32x16;

#define BATCH 4096
#define DIM 1024
#define ODIM 1024
#define K3 3072   // 3 * DIM (x^3 | x^2 | x)

// workspace layout (bytes)
#define WS_P      0          // bf16 [4096][3072] = 25165824
// pmin/pmax are TEMPORARY aliases inside the P region: they are fully
// consumed by k_minmax_final before k_prep writes P (stream-ordered).
#define WS_PMIN   0          // f32 [256][1024] = 1 MB
#define WS_PMAX   1048576    // f32 [256][1024] = 1 MB
#define WS_CB     25165824   // bf16 [1024][3072] = 6291456
#define WS_BIAS   31457280   // f32  [1024]
#define WS_MINV   31461376   // f32  [1024]
#define WS_SCALE  31465472   // f32  [1024]

#define ASYNC16(g, l)                                                          \
  __builtin_amdgcn_global_load_lds(                                            \
      (__attribute__((address_space(1))) void*)(g),                            \
      (__attribute__((address_space(3))) void*)(l), 16, 0, 0)

// ---- kernel 1: per-chunk column min/max (256 chunks of 16 rows, f32x4) ----
__global__ void k_minmax_part(const float* __restrict__ x,
                              float* __restrict__ pmin,
                              float* __restrict__ pmax) {
  const int t = threadIdx.x;   // 256 threads: cols 4t..4t+3
  const int ch = blockIdx.x;   // 256 chunks of 16 rows
  const float* p = x + (size_t)ch * 16 * DIM + (t << 2);
  f32x4 mn = {1e30f, 1e30f, 1e30f, 1e30f};
  f32x4 mx = {-1e30f, -1e30f, -1e30f, -1e30f};
#pragma unroll
  for (int r = 0; r < 16; ++r) {
    f32x4 v = *(const f32x4*)(p + (size_t)r * DIM);
#pragma unroll
    for (int j = 0; j < 4; ++j) {
      mn[j] = fminf(mn[j], v[j]);
      mx[j] = fmaxf(mx[j], v[j]);
    }
  }
  *(f32x4*)(pmin + ch * DIM + (t << 2)) = mn;
  *(f32x4*)(pmax + ch * DIM + (t << 2)) = mx;
}

// ---- kernel 2: final reduce + scale ----
__global__ void k_minmax_final(const float* __restrict__ pmin,
                               const float* __restrict__ pmax,
                               float* __restrict__ minv,
                               float* __restrict__ scale) {
  int col = blockIdx.x * 256 + threadIdx.x;
  float mn = 1e30f, mx = -1e30f;
#pragma unroll 8
  for (int ch = 0; ch < 256; ++ch) {
    mn = fminf(mn, pmin[ch * DIM + col]);
    mx = fmaxf(mx, pmax[ch * DIM + col]);
  }
  minv[col] = mn;
  scale[col] = 1.0f / (mx - mn);
}

// ---- kernel 3 (fused): powers (blocks 0..4095) + coeff reduce (blocks 4096..5119)
__global__ void k_prep(const float* __restrict__ x,
                       const float* __restrict__ minv,
                       const float* __restrict__ scale,
                       bf16* __restrict__ P,
                       const float* __restrict__ sp,
                       bf16* __restrict__ CB,
                       float* __restrict__ bias) {
  __shared__ float red[4];
  const int t = threadIdx.x;
  if (blockIdx.x < BATCH) {
    const int b = blockIdx.x;
    const int d = t << 2;
    f32x4 xv = *(const f32x4*)(x + (size_t)b * DIM + d);
    f32x4 mn = *(const f32x4*)(minv + d);
    f32x4 sc = *(const f32x4*)(scale + d);
    bf16x4 o3, o2, o1;
#pragma unroll
    for (int j = 0; j < 4; ++j) {
      float xn = (xv[j] - mn[j]) * sc[j];
      float x2 = xn * xn;
      float x3 = x2 * xn;
      o3[j] = (bf16)x3;
      o2[j] = (bf16)x2;
      o1[j] = (bf16)xn;
    }
    size_t base = (size_t)b * K3 + d;
    *(bf16x4*)(P + base) = o3;
    *(bf16x4*)(P + base + 1024) = o2;
    *(bf16x4*)(P + base + 2048) = o1;
  } else {
    const int o = blockIdx.x - BATCH;
    const int d = t << 2;
    f32x4 s[4];
#pragma unroll
    for (int dd = 0; dd < 4; ++dd) {
      const float* p = sp + ((size_t)o * DIM + d + dd) * 16;  // [s=4][4]
      f32x4 acc = *(const f32x4*)(p);
      acc += *(const f32x4*)(p + 4);
      acc += *(const f32x4*)(p + 8);
      acc += *(const f32x4*)(p + 12);
      s[dd] = acc;
    }
    size_t cb = (size_t)o * K3 + d;
    bf16x4 c0 = {(bf16)s[0][0], (bf16)s[1][0], (bf16)s[2][0], (bf16)s[3][0]};
    bf16x4 c1 = {(bf16)s[0][1], (bf16)s[1][1], (bf16)s[2][1], (bf16)s[3][1]};
    bf16x4 c2 = {(bf16)s[0][2], (bf16)s[1][2], (bf16)s[2][2], (bf16)s[3][2]};
    *(bf16x4*)(CB + cb) = c0;
    *(bf16x4*)(CB + cb + 1024) = c1;
    *(bf16x4*)(CB + cb + 2048) = c2;
    float v = s[0][3] + s[1][3] + s[2][3] + s[3][3];
#pragma unroll
    for (int off = 32; off > 0; off >>= 1) v += __shfl_down(v, off, 64);
    int lane = t & 63, w = t >> 6;
    if (lane == 0) red[w] = v;
    __syncthreads();
    if (t == 0) bias[o] = red[0] + red[1] + red[2] + red[3];
  }
}

// ---- kernel 4: GEMM out[b][o] = P[b][:] . CB[o][:] + bias[o] ----
// 64x64 tile, BK=64, 4 waves each one 32x32 quadrant via mfma_f32_32x32x16_bf16.
// Grid 1024 (4 blocks/CU), XCD-swizzled so each XCD reuses 8 A-bands from L2.
// R2-proven single-buffer 2-barrier loop; XOR-swizzled LDS (16B units).
#define BM 64
#define BN 64
#define BKE 64   // K elems per iter; row = 128 B = 8 x 16B units
#define NIT (K3 / BKE)  // 48
__global__ __launch_bounds__(256, 4) void k_gemm(const bf16* __restrict__ P,
                                                 const bf16* __restrict__ CBm,
                                                 const float* __restrict__ bias,
                                                 float* __restrict__ out) {
  __shared__ bf16 sA[BM * BKE];  // 8 KB
  __shared__ bf16 sB[BN * BKE];  // 8 KB

  const int tid = threadIdx.x;
  const int wave = tid >> 6;
  const int lane = tid & 63;

  // XCD-aware block swizzle: xcd owns 8 consecutive M-bands x all 16 N-blocks.
  const int bid = blockIdx.x;          // 0..1023
  const int xcd = bid & 7;
  const int local = bid >> 3;          // 0..127
  const int bm = (xcd * 8 + (local >> 4)) * BM;
  const int bn = (local & 15) * BN;

  const int wr = (wave >> 1) * 32;  // wave row origin (M)
  const int wc = (wave & 1) * 32;   // wave col origin (N)

  const size_t rowbytes = (size_t)K3 * 2;  // 6144

  // staging: A tile = 64 rows x 128 B = 8 KB = 2 issue-groups of 4 KB; B same.
  // LDS slot (row, q) holds global 16B unit (row, q^(row&7)).
  const char* gAp[2];
  const char* gBp[2];
  int ldso[2];
#pragma unroll
  for (int i = 0; i < 2; ++i) {
    int off = i * 4096 + tid * 16;
    int row = off >> 7;   // 128B rows
    int q = (off >> 4) & 7;
    int gb = (q ^ (row & 7)) * 16;
    gAp[i] = (const char*)P + (size_t)(bm + row) * rowbytes + gb;
    gBp[i] = (const char*)CBm + (size_t)(bn + row) * rowbytes + gb;
    ldso[i] = i * 4096 + wave * 1024;  // wave-uniform base; HW adds lane*16
  }

  f32x16 acc = {};

  // A-operand layout for 32x32x16: lane holds A[m = lane&31][k = (lane>>5)*8 + j]
  const int frow = lane & 31;
  const int fk = lane >> 5;  // 16B-unit parity within a 16-elem k-window

  for (int k0 = 0; k0 < K3; k0 += BKE) {
    const size_t kb = (size_t)k0 * 2;
#pragma unroll
    for (int i = 0; i < 2; ++i) ASYNC16(gAp[i] + kb, (char*)sA + ldso[i]);
#pragma unroll
    for (int i = 0; i < 2; ++i) ASYNC16(gBp[i] + kb, (char*)sB + ldso[i]);
    __syncthreads();

#pragma unroll
    for (int ks = 0; ks < 4; ++ks) {
      int ra = wr + frow;
      int ua = (ks * 2 + fk) ^ (ra & 7);
      bf16x8 af = *(const bf16x8*)&sA[ra * BKE + ua * 8];
      int rb = wc + frow;
      int ub = (ks * 2 + fk) ^ (rb & 7);
      bf16x8 bg = *(const bf16x8*)&sB[rb * BKE + ub * 8];
      acc = __builtin_amdgcn_mfma_f32_32x32x16_bf16(af, bg, acc, 0, 0, 0);
    }
    __syncthreads();
  }

  // epilogue: 32x32 C/D layout col=lane&31, row=(reg&3)+8*(reg>>2)+4*(lane>>5)
  const int col = bn + wc + (lane & 31);
  const float bv = bias[col];
  const int rbase = bm + wr + 4 * (lane >> 5);
#pragma unroll
  for (int r = 0; r < 16; ++r) {
    int row = rbase + (r & 3) + 8 * (r >> 2);
    out[(size_t)row * ODIM + col] = acc[r] + bv;
  }
}

extern "C" void kernel_launch(void* const* d_in, const int* in_sizes, int n_in,
                              void* d_out, int out_size, void* d_ws, size_t ws_size,
                              hipStream_t stream) {
  (void)in_sizes; (void)n_in; (void)out_size; (void)ws_size;
  const float* x = (const float*)d_in[0];
  const float* sp = (const float*)d_in[1];
  float* out = (float*)d_out;
  char* ws = (char*)d_ws;

  bf16* Pm = (bf16*)(ws + WS_P);
  bf16* CBm = (bf16*)(ws + WS_CB);
  float* bias = (float*)(ws + WS_BIAS);
  float* pmin = (float*)(ws + WS_PMIN);
  float* pmax = (float*)(ws + WS_PMAX);
  float* minv = (float*)(ws + WS_MINV);
  float* scale = (float*)(ws + WS_SCALE);

  k_minmax_part<<<256, 256, 0, stream>>>(x, pmin, pmax);
  k_minmax_final<<<4, 256, 0, stream>>>(pmin, pmax, minv, scale);
  k_prep<<<BATCH + ODIM, 256, 0, stream>>>(x, minv, scale, Pm, sp, CBm, bias);
  k_gemm<<<1024, 256, 0, stream>>>(Pm, CBm, bias, out);
}

// Round 5
// 180.254 us; speedup vs baseline: 1.0059x; 1.0059x over previous
//
#include <hip/hip_runtime.h>
#include <hip/hip_bf16.h>
#include <stdint.h>
#include <stddef.h>

typedef __bf16 bf16;
typedef __attribute__((ext_vector_type(4))) __bf16 bf16x4;
typedef __attribute__((ext_vector_type(8))) __bf16 bf16x8;
typedef __attribute__((ext_vector_type(4))) float f32x4;

#define BATCH 4096
#define DIM 1024
#define ODIM 1024
#define K3 3072   // 3 * DIM (x^3 | x^2 | x)

// workspace layout (bytes)
#define WS_P      0          // bf16 [4096][3072] = 25165824
// pmin/pmax alias the P region: fully consumed by k_minmax_final before
// k_prep writes P (stream-ordered).
#define WS_PMIN   0          // f32 [256][1024] = 1 MB
#define WS_PMAX   1048576    // f32 [256][1024] = 1 MB
#define WS_CB     25165824   // bf16 [1024][3072] = 6291456
#define WS_BIAS   31457280   // f32  [1024]
#define WS_MINV   31461376   // f32  [1024]
#define WS_SCALE  31465472   // f32  [1024]

#define ASYNC16(g, l)                                                          \
  __builtin_amdgcn_global_load_lds(                                            \
      (__attribute__((address_space(1))) void*)(g),                            \
      (__attribute__((address_space(3))) void*)(l), 16, 0, 0)

// ---- kernel 1: per-chunk column min/max (256 chunks of 16 rows, f32x4) ----
__global__ void k_minmax_part(const float* __restrict__ x,
                              float* __restrict__ pmin,
                              float* __restrict__ pmax) {
  const int t = threadIdx.x;   // cols 4t..4t+3
  const int ch = blockIdx.x;   // 256 chunks of 16 rows
  const float* p = x + (size_t)ch * 16 * DIM + (t << 2);
  f32x4 mn = {1e30f, 1e30f, 1e30f, 1e30f};
  f32x4 mx = {-1e30f, -1e30f, -1e30f, -1e30f};
#pragma unroll
  for (int r = 0; r < 16; ++r) {
    f32x4 v = *(const f32x4*)(p + (size_t)r * DIM);
#pragma unroll
    for (int j = 0; j < 4; ++j) {
      mn[j] = fminf(mn[j], v[j]);
      mx[j] = fmaxf(mx[j], v[j]);
    }
  }
  *(f32x4*)(pmin + ch * DIM + (t << 2)) = mn;
  *(f32x4*)(pmax + ch * DIM + (t << 2)) = mx;
}

// ---- kernel 2: final reduce + scale (64 blocks, 16 threads/col, coalesced) ----
__global__ void k_minmax_final(const float* __restrict__ pmin,
                               const float* __restrict__ pmax,
                               float* __restrict__ minv,
                               float* __restrict__ scale) {
  __shared__ float smn[16][17], smx[16][17];
  const int t = threadIdx.x;
  const int g = blockIdx.x;        // 16 cols per block
  const int cl = t & 15;           // col within block
  const int cs = t >> 4;           // chunk-slice 0..15
  const int col = g * 16 + cl;
  float mn = 1e30f, mx = -1e30f;
#pragma unroll
  for (int c = 0; c < 16; ++c) {
    int ch = cs * 16 + c;
    mn = fminf(mn, pmin[ch * DIM + col]);
    mx = fmaxf(mx, pmax[ch * DIM + col]);
  }
  smn[cs][cl] = mn;
  smx[cs][cl] = mx;
  __syncthreads();
  if (t < 16) {
    float m1 = smn[0][t], m2 = smx[0][t];
#pragma unroll
    for (int i = 1; i < 16; ++i) {
      m1 = fminf(m1, smn[i][t]);
      m2 = fmaxf(m2, smx[i][t]);
    }
    minv[g * 16 + t] = m1;
    scale[g * 16 + t] = 1.0f / (m2 - m1);
  }
}

// ---- kernel 3 (fused): powers (blocks 0..1023, 4 rows each) +
//                        coeff reduce (blocks 1024..2047, one o each) ----
__global__ void k_prep(const float* __restrict__ x,
                       const float* __restrict__ minv,
                       const float* __restrict__ scale,
                       bf16* __restrict__ P,
                       const float* __restrict__ sp,
                       bf16* __restrict__ CB,
                       float* __restrict__ bias) {
  __shared__ float red[4];
  const int t = threadIdx.x;
  if (blockIdx.x < 1024) {
    const int b0 = blockIdx.x << 2;  // 4 rows per block
    const int d = t << 2;
    f32x4 mn = *(const f32x4*)(minv + d);
    f32x4 sc = *(const f32x4*)(scale + d);
#pragma unroll
    for (int i = 0; i < 4; ++i) {
      const int b = b0 + i;
      f32x4 xv = *(const f32x4*)(x + (size_t)b * DIM + d);
      bf16x4 o3, o2, o1;
#pragma unroll
      for (int j = 0; j < 4; ++j) {
        float xn = (xv[j] - mn[j]) * sc[j];
        float x2 = xn * xn;
        float x3 = x2 * xn;
        o3[j] = (bf16)x3;
        o2[j] = (bf16)x2;
        o1[j] = (bf16)xn;
      }
      size_t base = (size_t)b * K3 + d;
      *(bf16x4*)(P + base) = o3;
      *(bf16x4*)(P + base + 1024) = o2;
      *(bf16x4*)(P + base + 2048) = o1;
    }
  } else {
    const int o = blockIdx.x - 1024;
    const int d = t << 2;
    f32x4 s[4];
#pragma unroll
    for (int dd = 0; dd < 4; ++dd) {
      const float* p = sp + ((size_t)o * DIM + d + dd) * 16;  // [s=4][4]
      f32x4 acc = *(const f32x4*)(p);
      acc += *(const f32x4*)(p + 4);
      acc += *(const f32x4*)(p + 8);
      acc += *(const f32x4*)(p + 12);
      s[dd] = acc;
    }
    size_t cb = (size_t)o * K3 + d;
    bf16x4 c0 = {(bf16)s[0][0], (bf16)s[1][0], (bf16)s[2][0], (bf16)s[3][0]};
    bf16x4 c1 = {(bf16)s[0][1], (bf16)s[1][1], (bf16)s[2][1], (bf16)s[3][1]};
    bf16x4 c2 = {(bf16)s[0][2], (bf16)s[1][2], (bf16)s[2][2], (bf16)s[3][2]};
    *(bf16x4*)(CB + cb) = c0;
    *(bf16x4*)(CB + cb + 1024) = c1;
    *(bf16x4*)(CB + cb + 2048) = c2;
    float v = s[0][3] + s[1][3] + s[2][3] + s[3][3];
#pragma unroll
    for (int off = 32; off > 0; off >>= 1) v += __shfl_down(v, off, 64);
    int lane = t & 63, w = t >> 6;
    if (lane == 0) red[w] = v;
    __syncthreads();
    if (t == 0) bias[o] = red[0] + red[1] + red[2] + red[3];
  }
}

// ---- kernel 4: GEMM out[b][o] = P[b][:] . CB[o][:] + bias[o] ----
// 128x128 tile, BK=64, 4 waves each 64x64 (4x4 frags of 16x16x32 — the
// R2-proven zero-conflict swizzled read pattern). Single-buffer 2-barrier
// loop. Grid (32,8): same-A-band blocks are congruent mod 8 -> same XCD.
#define BM 128
#define BN 128
#define BKE 64   // K elems per iter; row = 128 B = 8 x 16B units
#define NIT (K3 / BKE)  // 48
__global__ __launch_bounds__(256, 1) void k_gemm(const bf16* __restrict__ P,
                                                 const bf16* __restrict__ CBm,
                                                 const float* __restrict__ bias,
                                                 float* __restrict__ out) {
  __shared__ bf16 sA[BM * BKE];  // 16 KB
  __shared__ bf16 sB[BN * BKE];  // 16 KB

  const int tid = threadIdx.x;
  const int wave = tid >> 6;
  const int lane = tid & 63;
  const int bm = blockIdx.x * BM;
  const int bn = blockIdx.y * BN;
  const int wr = (wave >> 1) * 64;  // wave row origin (M)
  const int wc = (wave & 1) * 64;   // wave col origin (N)

  const size_t rowbytes = (size_t)K3 * 2;  // 6144

  // staging: A tile = 128 rows x 128 B = 16 KB = 4 issue-groups of 4 KB; B same.
  // LDS slot (row, q) holds global 16B unit (row, q^(row&7)).
  const char* gAp[4];
  const char* gBp[4];
  int ldso[4];
#pragma unroll
  for (int i = 0; i < 4; ++i) {
    int off = i * 4096 + tid * 16;
    int row = off >> 7;   // 128B rows
    int q = (off >> 4) & 7;
    int gb = (q ^ (row & 7)) * 16;
    gAp[i] = (const char*)P + (size_t)(bm + row) * rowbytes + gb;
    gBp[i] = (const char*)CBm + (size_t)(bn + row) * rowbytes + gb;
    ldso[i] = i * 4096 + wave * 1024;  // wave-uniform base; HW adds lane*16
  }

  f32x4 acc[4][4] = {};

  const int mrow = lane & 15;
  const int kq = lane >> 4;  // 16B-unit index within a 32-elem k-window

  for (int k0 = 0; k0 < K3; k0 += BKE) {
    const size_t kb = (size_t)k0 * 2;
#pragma unroll
    for (int i = 0; i < 4; ++i) ASYNC16(gAp[i] + kb, (char*)sA + ldso[i]);
#pragma unroll
    for (int i = 0; i < 4; ++i) ASYNC16(gBp[i] + kb, (char*)sB + ldso[i]);
    __syncthreads();

#pragma unroll
    for (int ks = 0; ks < 2; ++ks) {
      bf16x8 af[4], bg[4];
#pragma unroll
      for (int i = 0; i < 4; ++i) {
        int row = wr + i * 16 + mrow;
        int sq = (ks * 4 + kq) ^ (row & 7);
        af[i] = *(const bf16x8*)&sA[row * BKE + sq * 8];
      }
#pragma unroll
      for (int j = 0; j < 4; ++j) {
        int row = wc + j * 16 + mrow;
        int sq = (ks * 4 + kq) ^ (row & 7);
        bg[j] = *(const bf16x8*)&sB[row * BKE + sq * 8];
      }
#pragma unroll
      for (int i = 0; i < 4; ++i)
#pragma unroll
        for (int j = 0; j < 4; ++j)
          acc[i][j] = __builtin_amdgcn_mfma_f32_16x16x32_bf16(af[i], bg[j],
                                                              acc[i][j], 0, 0, 0);
    }
    __syncthreads();
  }

  // epilogue: C/D layout col=lane&15, row=(lane>>4)*4+reg
  const int ccol = lane & 15;
  const int crow = (lane >> 4) * 4;
#pragma unroll
  for (int j = 0; j < 4; ++j) {
    const int col = bn + wc + j * 16 + ccol;
    const float bv = bias[col];
#pragma unroll
    for (int i = 0; i < 4; ++i) {
      const int row0 = bm + wr + i * 16 + crow;
#pragma unroll
      for (int r = 0; r < 4; ++r)
        out[(size_t)(row0 + r) * ODIM + col] = acc[i][j][r] + bv;
    }
  }
}

extern "C" void kernel_launch(void* const* d_in, const int* in_sizes, int n_in,
                              void* d_out, int out_size, void* d_ws, size_t ws_size,
                              hipStream_t stream) {
  (void)in_sizes; (void)n_in; (void)out_size; (void)ws_size;
  const float* x = (const float*)d_in[0];
  const float* sp = (const float*)d_in[1];
  float* out = (float*)d_out;
  char* ws = (char*)d_ws;

  bf16* Pm = (bf16*)(ws + WS_P);
  bf16* CBm = (bf16*)(ws + WS_CB);
  float* bias = (float*)(ws + WS_BIAS);
  float* pmin = (float*)(ws + WS_PMIN);
  float* pmax = (float*)(ws + WS_PMAX);
  float* minv = (float*)(ws + WS_MINV);
  float* scale = (float*)(ws + WS_SCALE);

  k_minmax_part<<<256, 256, 0, stream>>>(x, pmin, pmax);
  k_minmax_final<<<64, 256, 0, stream>>>(pmin, pmax, minv, scale);
  k_prep<<<2048, 256, 0, stream>>>(x, minv, scale, Pm, sp, CBm, bias);
  k_gemm<<<dim3(32, 8), 256, 0, stream>>>(Pm, CBm, bias, out);
}